// Round 1
// baseline (494.523 us; speedup 1.0000x reference)
//
#include <hip/hip_runtime.h>
#include <hip/hip_bf16.h>

// TaylorMap, symmetric-packed quadratic, uniform-9 pair stream (bf16).
// R13 = R12 core + overlap package targeting the fill<->MFMA serialization:
//   (1) __launch_bounds__(512,2): true occupancy is 2 waves/SIMD (grid=256
//       blocks on 256 CUs, LDS 84.5KB -> 1 block/CU). Declaring it lifts the
//       128-VGPR cap that made R11's +32-reg attempt spill.
//   (2) 2-pair-deep A prefetch: bufA/bufB ping-pong, reload targets pair q+2
//       (18 slices in flight/wave) so transient L1-fill backup no longer
//       stalls every pair boundary on vmcnt.
//   (3) cross-step prefetch: stream-tail reloads (previously garbage pair-32
//       reads) fetch the NEXT step's pairs 0/1 -> pipeline never restarts
//       cold after the step barriers. All tail loads in-bounds by construction.
//   (4) symmetric merge: g0 publishes acc1 / merges+writes cols 0..31, g1
//       publishes acc0 / merges+writes cols 32..63 -> C->A phase halves and
//       parallelizes (g1 no longer idles).
//   (5) s_setprio(1) around MFMA chains, 0 during chain-end fmacs, so the
//       co-wave's MFMAs win issue arbitration during VALU stretches.
// Model: per CU per step MFMA floor ~37.7k cyc ~= A-fill floor (2.4MB from
// L2); measured wall ~84k cyc ~= their SUM. This package converts sum->max.

#define DSTATE 128
#define BATCH  16384
#define NSTEPS 7
#define BT     64
#define NSL    585          // slices per d-tile: 64*9 pair + 8 linear + 1 pad

typedef __attribute__((ext_vector_type(8)))  short  short8;   // 8 bf16 = 4 VGPRs
typedef __attribute__((ext_vector_type(16))) float  f32x16;   // MFMA 32x32 C/D

__device__ __forceinline__ unsigned short f2bf(float f){
    unsigned int u = __float_as_uint(f);
    u += 0x7fff + ((u >> 16) & 1);          // RNE
    return (unsigned short)(u >> 16);
}

// Pack symmetric-folded W into bf16 MFMA-A fragments, uniform-9 pair stream.
// Pair p at positions 9p..9p+8: first 8-(p>>4) slices are row p (j-blocks
// p>>4..7), remaining 1+(p>>4) are row 127-p (j-blocks 7-(p>>4)..7).
// Fragment layout: A[m][k], m=lane&31 -> d=32t+m, k=(lane>>5)*8+e -> j=16*s+k.
__global__ void prep_kernel(const float* __restrict__ W, short8* __restrict__ A){
    int gid = blockIdx.x * 256 + threadIdx.x;
    const int ntotal = 4 * 130 * 8 * 64;
    if (gid >= ntotal) return;
    int lane = gid & 63; int r = gid >> 6;
    int s = r & 7;  r >>= 3;
    int row = r % 130;
    int t   = r / 130;
    int d  = t * 32 + (lane & 31);
    int kb = (lane >> 5) * 8;
    int dst;
    bool zero = false;
    if (row < 64){
        int sl = row >> 4;
        if (s < sl) return;
        dst = t * NSL + 9 * row + (s - sl);
    } else if (row < 128){
        int p  = 127 - row;
        int sl = row >> 4;
        if (s < sl) return;
        int ca = 8 - (p >> 4);
        dst = t * NSL + 9 * p + ca + (s - sl);
    } else if (row == 128){
        dst = t * NSL + 576 + s;               // linear (W1) row
    } else {
        if (s) return;                         // zero pad slice
        dst = t * NSL + 584;
        zero = true;
    }
    union { short8 v; unsigned short u[8]; } fr;
#pragma unroll
    for (int e = 0; e < 8; ++e){
        int j = s * 16 + kb + e;
        float v;
        if (zero) v = 0.0f;
        else if (row < 128){
            if      (j < row)  v = 0.0f;
            else if (j == row) v = W[(129 + 128 * row + j) * 128 + d];
            else               v = W[(129 + 128 * row + j) * 128 + d]
                                 + W[(129 + 128 * j + row) * 128 + d];
        } else {
            v = W[(1 + j) * 128 + d];
        }
        fr.u[e] = f2bf(v);
    }
    A[(size_t)dst * 64 + lane] = fr.v;
}

// Per-pair body. BUF = ping-pong buffer consumed for pair pp; every slot is
// reloaded from RLD (slot s <- RLD[s*64]), i.e. prefetch distance 2 pairs in
// the main loop (RLD = ap -> pair pp+2) or the cross-step target in tails.
#define QBODY(BK, BUF, pp, RLD)                                                 \
{                                                                               \
    const int p_ = (pp);                                                        \
    float s0a = x_lds[p_ * BT + ln];                                            \
    float s0b = x_lds[p_ * BT + 32 + ln];                                       \
    float s1a = x_lds[(127 - p_) * BT + ln];                                    \
    float s1b = x_lds[(127 - p_) * BT + 32 + ln];                               \
    f32x16 Y0, Y1;                                                              \
    __builtin_amdgcn_s_setprio(1);                                              \
    _Pragma("unroll")                                                           \
    for (int s = 0; s < 8 - (BK); ++s){                                         \
        Y0 = __builtin_amdgcn_mfma_f32_32x32x16_bf16(BUF[s], bfrag0[s], s ? Y0 : zero16, 0, 0, 0); \
        Y1 = __builtin_amdgcn_mfma_f32_32x32x16_bf16(BUF[s], bfrag1[s], s ? Y1 : zero16, 0, 0, 0); \
        BUF[s] = (RLD)[s * 64];                                                 \
    }                                                                           \
    __builtin_amdgcn_s_setprio(0);                                              \
    acc0 += s0a * Y0;                                                           \
    acc1 += s0b * Y1;                                                           \
    f32x16 Z0, Z1;                                                              \
    __builtin_amdgcn_s_setprio(1);                                              \
    _Pragma("unroll")                                                           \
    for (int s = 0; s < 1 + (BK); ++s){                                         \
        Z0 = __builtin_amdgcn_mfma_f32_32x32x16_bf16(BUF[8 - (BK) + s], bfrag0[7 - 2 * (BK) + s], s ? Z0 : zero16, 0, 0, 0); \
        Z1 = __builtin_amdgcn_mfma_f32_32x32x16_bf16(BUF[8 - (BK) + s], bfrag1[7 - 2 * (BK) + s], s ? Z1 : zero16, 0, 0, 0); \
        BUF[8 - (BK) + s] = (RLD)[(8 - (BK) + s) * 64];                         \
    }                                                                           \
    __builtin_amdgcn_s_setprio(0);                                              \
    acc0 += s1a * Z0;                                                           \
    acc1 += s1b * Z1;                                                           \
}

// One 16-pair block (NQQ pair-of-pairs; tails peeled by the caller).
#define PAIRS2(BK, NQQ)                                                         \
    _Pragma("unroll")                                                           \
    for (int s = 0; s < 8 - (BK); ++s){                                         \
        bfrag0[s] = bpack[((BK) + s) * 64 + lane];                              \
        bfrag1[s] = bpack[512 + ((BK) + s) * 64 + lane];                        \
    }                                                                           \
    _Pragma("unroll 1")                                                         \
    for (int qq = 0; qq < (NQQ); ++qq){                                         \
        QBODY(BK, bufA, 16 * (BK) + 2 * qq,     ap) ap += 9 * 64;               \
        QBODY(BK, bufB, 16 * (BK) + 2 * qq + 1, ap) ap += 9 * 64;               \
    }

__global__ __launch_bounds__(512, 2)
void taylor_kernel(const float* __restrict__ X, const float* __restrict__ W,
                   const float* __restrict__ tini, const float* __restrict__ lini,
                   const short8* __restrict__ A, float* __restrict__ out)
{
    __shared__ float  x_lds[DSTATE * BT];      // fp32 master state [d][b], 32 KB
    __shared__ float  w0_lds[DSTATE];
    __shared__ short8 bpack[2 * 8 * 64];       // B frags, 2 groups x 8 slices, 16 KB
    __shared__ float  sc_lds[2][4 * 64 * 17];  // K-merge scratch, 34.8 KB

    const int tid  = threadIdx.x;
    const int lane = tid & 63;
    const int w    = tid >> 6;
    const int t    = w & 3;                    // d-tile
    const int g    = w >> 2;                   // K-half (pairs 0..31 / 32..63+lin)
    const int ln   = lane & 31;
    const int hi   = lane >> 5;
    const int b0   = blockIdx.x * BT;

    // ---- init x0 = [X | t_init | l_init] ----
#pragma unroll
    for (int it = 0; it < 16; ++it){
        int entry = tid + it * 512;            // entry = b*128 + d
        int b = entry >> 7, d = entry & 127;
        float v;
        if      (d < 120) v = X[(b0 + b) * 120 + d];
        else if (d < 124) v = tini[d - 120];
        else              v = lini[d - 124];
        x_lds[d * BT + b] = v;
    }
    if (tid < DSTATE) w0_lds[tid] = W[tid];

    // wave's half-stream base: g0 -> slice 0, g1 -> slice 288 (pair 32)
    const short8* const Aw = A + ((size_t)t * NSL + (size_t)g * 288) * 64 + lane;
    const f32x16 zero16 = {};

    // ---- 2-pair-deep A pipeline, loop-carried across steps ----
    short8 bufA[9], bufB[9];
#pragma unroll
    for (int s = 0; s < 9; ++s){
        bufA[s] = Aw[s * 64];                  // pair 0 of this wave's stream
        bufB[s] = Aw[(9 + s) * 64];            // pair 1
    }

#pragma unroll 1
    for (int step = 0; step < NSTEPS; ++step){
        __syncthreads();                       // (A) x_lds stable

        // last-step pruning: only d-tile 3 feeds out dims 120..123
        const bool active = (step < NSTEPS - 1) || (t == 3);

        // ---- build bpack (1024 frags, 2 per thread) ----
#pragma unroll
        for (int f0 = 0; f0 < 2; ++f0){
            int f  = tid + f0 * 512;
            int gg = f >> 9, s = (f >> 6) & 7, l = f & 63;
            int c  = gg * 32 + (l & 31);
            int jb = 16 * s + 8 * (l >> 5);
            union { short8 v; unsigned short u[8]; } fr;
#pragma unroll
            for (int e = 0; e < 8; ++e)
                fr.u[e] = f2bf(x_lds[(jb + e) * BT + c]);
            bpack[f] = fr.v;
        }

        // ---- symmetric init: g0 seeds cols 0..31, g1 seeds cols 32..63 ----
        f32x16 acc0, acc1;
        if (active){
            if (g == 0){
#pragma unroll
                for (int r = 0; r < 16; ++r){
                    int d = 32 * t + (r & 3) + 8 * (r >> 2) + 4 * hi;
                    acc0[r] = x_lds[d * BT + ln] + w0_lds[d];
                    acc1[r] = 0.f;
                }
            } else {
#pragma unroll
                for (int r = 0; r < 16; ++r){
                    int d = 32 * t + (r & 3) + 8 * (r >> 2) + 4 * hi;
                    acc0[r] = 0.f;
                    acc1[r] = x_lds[d * BT + 32 + ln] + w0_lds[d];
                }
            }
        }

        __syncthreads();                       // (B) bpack visible

        if (active){
            const short8* ap = Aw + 18 * 64;   // reload cursor -> pair 2
            short8 bfrag0[8], bfrag1[8];

            if (g == 0){
                PAIRS2(0, 8)
                PAIRS2(1, 7)
                // peeled tails: reload = NEXT STEP pairs 0/1 (in-bounds always;
                // harmless dummy when next step prunes this wave)
                QBODY(1, bufA, 30, Aw)
                QBODY(1, bufB, 31, Aw + 9 * 64)
                // publish K-half-0 partial for cols 32..63
#pragma unroll
                for (int r = 0; r < 16; ++r)
                    sc_lds[1][(t * 64 + lane) * 17 + r] = acc1[r];
            } else {
                PAIRS2(2, 8)
                PAIRS2(3, 7)
                // tail q=62 reload is the normal stream continuation: it pulls
                // the linear slices 576..584 into bufA (consumed below).
                QBODY(3, bufA, 62, ap)
                // tail q=63 reload -> next step's pair 1 (slices 297..305)
                QBODY(3, bufB, 63, Aw + 9 * 64)
                // linear (W1) row: scale==1 -> accumulate DIRECTLY into acc
                // via the MFMA C-operand (bufA holds slices 576..583 + pad)
#pragma unroll
                for (int s = 0; s < 8; ++s){
                    bfrag0[s] = bpack[s * 64 + lane];
                    bfrag1[s] = bpack[512 + s * 64 + lane];
                }
                __builtin_amdgcn_s_setprio(1);
#pragma unroll
                for (int s = 0; s < 8; ++s){
                    acc0 = __builtin_amdgcn_mfma_f32_32x32x16_bf16(bufA[s], bfrag0[s], acc0, 0, 0, 0);
                    acc1 = __builtin_amdgcn_mfma_f32_32x32x16_bf16(bufA[s], bfrag1[s], acc1, 0, 0, 0);
                }
                __builtin_amdgcn_s_setprio(0);
                // refill bufA with next step's pair 0 (slices 288..296)
#pragma unroll
                for (int s = 0; s < 9; ++s) bufA[s] = Aw[s * 64];
                // publish K-half-1 partial for cols 0..31
#pragma unroll
                for (int r = 0; r < 16; ++r)
                    sc_lds[0][(t * 64 + lane) * 17 + r] = acc0[r];
            }
        }

        __syncthreads();                       // (C) reads done + scratch visible

        // ---- symmetric merge: g0 finishes cols 0..31, g1 cols 32..63 ----
        if (active){
            if (g == 0){
#pragma unroll
                for (int r = 0; r < 16; ++r)
                    acc0[r] += sc_lds[0][(t * 64 + lane) * 17 + r];
                if (step < NSTEPS - 1){
#pragma unroll
                    for (int r = 0; r < 16; ++r){
                        int d = 32 * t + (r & 3) + 8 * (r >> 2) + 4 * hi;
                        x_lds[d * BT + ln] = acc0[r];
                    }
                } else if (hi == 0){
                    // out dims 120..123 -> tile 3, regs 12..15 @ hi==0
                    *(float4*)(out + (size_t)(b0 + ln) * 4) =
                        make_float4(acc0[12], acc0[13], acc0[14], acc0[15]);
                }
            } else {
#pragma unroll
                for (int r = 0; r < 16; ++r)
                    acc1[r] += sc_lds[1][(t * 64 + lane) * 17 + r];
                if (step < NSTEPS - 1){
#pragma unroll
                    for (int r = 0; r < 16; ++r){
                        int d = 32 * t + (r & 3) + 8 * (r >> 2) + 4 * hi;
                        x_lds[d * BT + 32 + ln] = acc1[r];
                    }
                } else if (hi == 0){
                    *(float4*)(out + (size_t)(b0 + 32 + ln) * 4) =
                        make_float4(acc1[12], acc1[13], acc1[14], acc1[15]);
                }
            }
        }
        // next iteration's barrier (A) orders x writes vs bpack reads
    }
}

extern "C" void kernel_launch(void* const* d_in, const int* in_sizes, int n_in,
                              void* d_out, int out_size, void* d_ws, size_t ws_size,
                              hipStream_t stream)
{
    const float* X  = (const float*)d_in[0];
    const float* W  = (const float*)d_in[1];
    const float* ti = (const float*)d_in[2];
    const float* li = (const float*)d_in[3];
    float* out      = (float*)d_out;
    short8* A       = (short8*)d_ws;           // 4*585*64*16 B = 2.40 MB

    const int ntotal = 4 * 130 * 8 * 64;
    prep_kernel<<<(ntotal + 255) / 256, 256, 0, stream>>>(W, A);
    taylor_kernel<<<BATCH / BT, 512, 0, stream>>>(X, W, ti, li, A, out);
}

// Round 2
// 321.836 us; speedup vs baseline: 1.5366x; 1.5366x over previous
//
#include <hip/hip_runtime.h>
#include <hip/hip_bf16.h>

// TaylorMap, symmetric-packed quadratic, uniform-9 pair stream (bf16).
// R14 = R12 core (single abuf[9], nothing loop-carried across barriers --
// the proven zero-spill 128-VGPR shape; R13's 2-deep pipeline spilled
// ~750 MB of scratch because the 128-reg cap is a hard wall) + three
// register-neutral convoy-breakers:
//   (1) g1 linear-first: g1 runs its 16-MFMA linear row BEFORE its pair
//       stream -> persistent ~516-cyc (half-q-round) skew between the two
//       waves co-resident on each SIMD (pairs are (t,g0)/(t,g1)). When one
//       stalls on vmcnt at a pair boundary the other is mid-MFMA-chain.
//   (2) s_setprio(1) around MFMA chains (0 during chain-end fmacs).
//   (3) symmetric merge (R13-verified): g0 publishes acc1 / finishes cols
//       0..31, g1 publishes acc0 / finishes cols 32..63.
// Discriminates H2 (convoy: fill+MFMA each ~1150 cyc/q, serialized by
// lockstep -> skew recovers toward max) vs H1 (L2->L1 streaming path is
// ~29 B/cyc/CU, MFMA already hidden -> neutral, 254 us is the roofline).

#define DSTATE 128
#define BATCH  16384
#define NSTEPS 7
#define BT     64
#define NSL    585          // slices per d-tile: 64*9 pair + 8 linear + 1 pad

typedef __attribute__((ext_vector_type(8)))  short  short8;   // 8 bf16 = 4 VGPRs
typedef __attribute__((ext_vector_type(16))) float  f32x16;   // MFMA 32x32 C/D

__device__ __forceinline__ unsigned short f2bf(float f){
    unsigned int u = __float_as_uint(f);
    u += 0x7fff + ((u >> 16) & 1);          // RNE
    return (unsigned short)(u >> 16);
}

// Pack symmetric-folded W into bf16 MFMA-A fragments, uniform-9 pair stream.
// Pair p at positions 9p..9p+8: first 8-(p>>4) slices are row p (j-blocks
// p>>4..7), remaining 1+(p>>4) are row 127-p (j-blocks 7-(p>>4)..7).
// Fragment layout: A[m][k], m=lane&31 -> d=32t+m, k=(lane>>5)*8+e -> j=16*s+k.
__global__ void prep_kernel(const float* __restrict__ W, short8* __restrict__ A){
    int gid = blockIdx.x * 256 + threadIdx.x;
    const int ntotal = 4 * 130 * 8 * 64;
    if (gid >= ntotal) return;
    int lane = gid & 63; int r = gid >> 6;
    int s = r & 7;  r >>= 3;
    int row = r % 130;
    int t   = r / 130;
    int d  = t * 32 + (lane & 31);
    int kb = (lane >> 5) * 8;
    int dst;
    bool zero = false;
    if (row < 64){
        int sl = row >> 4;
        if (s < sl) return;
        dst = t * NSL + 9 * row + (s - sl);
    } else if (row < 128){
        int p  = 127 - row;
        int sl = row >> 4;
        if (s < sl) return;
        int ca = 8 - (p >> 4);
        dst = t * NSL + 9 * p + ca + (s - sl);
    } else if (row == 128){
        dst = t * NSL + 576 + s;               // linear (W1) row
    } else {
        if (s) return;                         // zero pad slice
        dst = t * NSL + 584;
        zero = true;
    }
    union { short8 v; unsigned short u[8]; } fr;
#pragma unroll
    for (int e = 0; e < 8; ++e){
        int j = s * 16 + kb + e;
        float v;
        if (zero) v = 0.0f;
        else if (row < 128){
            if      (j < row)  v = 0.0f;
            else if (j == row) v = W[(129 + 128 * row + j) * 128 + d];
            else               v = W[(129 + 128 * row + j) * 128 + d]
                                 + W[(129 + 128 * j + row) * 128 + d];
        } else {
            v = W[(1 + j) * 128 + d];
        }
        fr.u[e] = f2bf(v);
    }
    A[(size_t)dst * 64 + lane] = fr.v;
}

__global__ __launch_bounds__(512)
void taylor_kernel(const float* __restrict__ X, const float* __restrict__ W,
                   const float* __restrict__ tini, const float* __restrict__ lini,
                   const short8* __restrict__ A, float* __restrict__ out)
{
    __shared__ float  x_lds[DSTATE * BT];      // fp32 master state [d][b], 32 KB
    __shared__ float  w0_lds[DSTATE];
    __shared__ short8 bpack[2 * 8 * 64];       // B frags, 2 groups x 8 slices, 16 KB
    __shared__ float  sc_lds[2][4 * 64 * 17];  // K-merge scratch, 34.8 KB

    const int tid  = threadIdx.x;
    const int lane = tid & 63;
    const int w    = tid >> 6;
    const int t    = w & 3;                    // d-tile
    const int g    = w >> 2;                   // K-half (pairs 0..31 / 32..63+lin)
    const int ln   = lane & 31;
    const int hi   = lane >> 5;
    const int b0   = blockIdx.x * BT;

    // ---- init x0 = [X | t_init | l_init] ----
#pragma unroll
    for (int it = 0; it < 16; ++it){
        int entry = tid + it * 512;            // entry = b*128 + d
        int b = entry >> 7, d = entry & 127;
        float v;
        if      (d < 120) v = X[(b0 + b) * 120 + d];
        else if (d < 124) v = tini[d - 120];
        else              v = lini[d - 124];
        x_lds[d * BT + b] = v;
    }
    if (tid < DSTATE) w0_lds[tid] = W[tid];

    // wave's half-stream base: g0 -> slice 0, g1 -> slice 288 (pair 32)
    const short8* const Aw   = A + ((size_t)t * NSL + (size_t)g * 288) * 64 + lane;
    const short8* const Alin = A + ((size_t)t * NSL + 576) * 64 + lane;
    const f32x16 zero16 = {};

#pragma unroll 1
    for (int step = 0; step < NSTEPS; ++step){
        __syncthreads();                       // (A) x_lds stable

        // last-step pruning: only d-tile 3 feeds out dims 120..123
        const bool active = (step < NSTEPS - 1) || (t == 3);

        const short8* ap = Aw;
        short8 abuf[9];
        if (active){
            if (g == 0){
#pragma unroll
                for (int s = 0; s < 9; ++s) abuf[s] = ap[s * 64];  // pair 0
                ap += 9 * 64;                                      // -> pair 1
            } else {
#pragma unroll
                for (int s = 0; s < 9; ++s) abuf[s] = Alin[s * 64]; // linear row
                // ap set to pair 33 after the linear chain refills abuf
            }
        }

        // ---- build bpack (1024 frags, 2 per thread) while loads fly ----
#pragma unroll
        for (int f0 = 0; f0 < 2; ++f0){
            int f  = tid + f0 * 512;
            int gg = f >> 9, s = (f >> 6) & 7, l = f & 63;
            int c  = gg * 32 + (l & 31);
            int jb = 16 * s + 8 * (l >> 5);
            union { short8 v; unsigned short u[8]; } fr;
#pragma unroll
            for (int e = 0; e < 8; ++e)
                fr.u[e] = f2bf(x_lds[(jb + e) * BT + c]);
            bpack[f] = fr.v;
        }

        // ---- symmetric init: g0 seeds cols 0..31, g1 seeds cols 32..63 ----
        f32x16 acc0, acc1;
        if (active){
            if (g == 0){
#pragma unroll
                for (int r = 0; r < 16; ++r){
                    int d = 32 * t + (r & 3) + 8 * (r >> 2) + 4 * hi;
                    acc0[r] = x_lds[d * BT + ln] + w0_lds[d];
                    acc1[r] = 0.f;
                }
            } else {
#pragma unroll
                for (int r = 0; r < 16; ++r){
                    int d = 32 * t + (r & 3) + 8 * (r >> 2) + 4 * hi;
                    acc0[r] = 0.f;
                    acc1[r] = x_lds[d * BT + 32 + ln] + w0_lds[d];
                }
            }
        }

        __syncthreads();                       // (B) bpack visible

        if (active){
            short8 bfrag0[8], bfrag1[8];       // B reg-cache for current BK block

            // R9 core: pair p=16*BK+q, rows (p,127-p). Y: slices BK..7
            // (abuf[0..7-BK]); Z: slices 7-BK..7 (abuf[8-BK..8], bfrag
            // 7-2BK+s). Immediate chain-end fmacs (proven zero-spill shape).
            // abuf[s] reloaded for the NEXT pair right after its consumers.
#define PAIRS(BK)                                                               \
            {                                                                   \
                _Pragma("unroll")                                               \
                for (int s = 0; s < 8 - (BK); ++s){                             \
                    bfrag0[s] = bpack[((BK) + s) * 64 + lane];                  \
                    bfrag1[s] = bpack[512 + ((BK) + s) * 64 + lane];            \
                }                                                               \
                _Pragma("unroll 2")                                             \
                for (int q = 0; q < 16; ++q){                                   \
                    const int p = 16 * (BK) + q;                                \
                    float s0a = x_lds[p * BT + ln];                             \
                    float s0b = x_lds[p * BT + 32 + ln];                        \
                    float s1a = x_lds[(127 - p) * BT + ln];                     \
                    float s1b = x_lds[(127 - p) * BT + 32 + ln];                \
                    f32x16 Y0, Y1;                                              \
                    __builtin_amdgcn_s_setprio(1);                              \
                    _Pragma("unroll")                                           \
                    for (int s = 0; s < 8 - (BK); ++s){                         \
                        Y0 = __builtin_amdgcn_mfma_f32_32x32x16_bf16(abuf[s], bfrag0[s], s ? Y0 : zero16, 0, 0, 0); \
                        Y1 = __builtin_amdgcn_mfma_f32_32x32x16_bf16(abuf[s], bfrag1[s], s ? Y1 : zero16, 0, 0, 0); \
                        abuf[s] = ap[s * 64];                                   \
                    }                                                           \
                    __builtin_amdgcn_s_setprio(0);                              \
                    acc0 += s0a * Y0;                                           \
                    acc1 += s0b * Y1;                                           \
                    f32x16 Z0, Z1;                                              \
                    __builtin_amdgcn_s_setprio(1);                              \
                    _Pragma("unroll")                                           \
                    for (int s = 0; s < 1 + (BK); ++s){                         \
                        Z0 = __builtin_amdgcn_mfma_f32_32x32x16_bf16(abuf[8 - (BK) + s], bfrag0[7 - 2 * (BK) + s], s ? Z0 : zero16, 0, 0, 0); \
                        Z1 = __builtin_amdgcn_mfma_f32_32x32x16_bf16(abuf[8 - (BK) + s], bfrag1[7 - 2 * (BK) + s], s ? Z1 : zero16, 0, 0, 0); \
                        abuf[8 - (BK) + s] = ap[(8 - (BK) + s) * 64];           \
                    }                                                           \
                    __builtin_amdgcn_s_setprio(0);                              \
                    acc0 += s1a * Z0;                                           \
                    acc1 += s1b * Z1;                                           \
                    ap += 9 * 64;                                               \
                }                                                               \
            }

            if (g == 0){
                PAIRS(0) PAIRS(1)
                // trailing reloads read pair 32 (in-bounds, discarded)
                // publish K-half-0 partial for cols 32..63
#pragma unroll
                for (int r = 0; r < 16; ++r)
                    sc_lds[1][(t * 64 + lane) * 17 + r] = acc1[r];
            } else {
                // ---- linear (W1) row FIRST: the phase-skew + direct C-op
                // accumulate. abuf holds slices 576..583 (+pad); reloads
                // pull pair 32 in behind the 16-MFMA chain. ----
#pragma unroll
                for (int s = 0; s < 8; ++s){
                    bfrag0[s] = bpack[s * 64 + lane];
                    bfrag1[s] = bpack[512 + s * 64 + lane];
                }
                __builtin_amdgcn_s_setprio(1);
#pragma unroll
                for (int s = 0; s < 8; ++s){
                    acc0 = __builtin_amdgcn_mfma_f32_32x32x16_bf16(abuf[s], bfrag0[s], acc0, 0, 0, 0);
                    acc1 = __builtin_amdgcn_mfma_f32_32x32x16_bf16(abuf[s], bfrag1[s], acc1, 0, 0, 0);
                    abuf[s] = Aw[s * 64];      // refill: pair 32
                }
                __builtin_amdgcn_s_setprio(0);
                abuf[8] = Aw[8 * 64];
                ap = Aw + 9 * 64;              // reload cursor -> pair 33
                PAIRS(2) PAIRS(3)
                // trailing reloads read slices 576..584 (in-bounds, discarded)
                // publish K-half-1 partial for cols 0..31
#pragma unroll
                for (int r = 0; r < 16; ++r)
                    sc_lds[0][(t * 64 + lane) * 17 + r] = acc0[r];
            }
#undef PAIRS
        }

        __syncthreads();                       // (C) reads done + scratch visible

        // ---- symmetric merge: g0 finishes cols 0..31, g1 cols 32..63 ----
        if (active){
            if (g == 0){
#pragma unroll
                for (int r = 0; r < 16; ++r)
                    acc0[r] += sc_lds[0][(t * 64 + lane) * 17 + r];
                if (step < NSTEPS - 1){
#pragma unroll
                    for (int r = 0; r < 16; ++r){
                        int d = 32 * t + (r & 3) + 8 * (r >> 2) + 4 * hi;
                        x_lds[d * BT + ln] = acc0[r];
                    }
                } else if (hi == 0){
                    // out dims 120..123 -> tile 3, regs 12..15 @ hi==0
                    *(float4*)(out + (size_t)(b0 + ln) * 4) =
                        make_float4(acc0[12], acc0[13], acc0[14], acc0[15]);
                }
            } else {
#pragma unroll
                for (int r = 0; r < 16; ++r)
                    acc1[r] += sc_lds[1][(t * 64 + lane) * 17 + r];
                if (step < NSTEPS - 1){
#pragma unroll
                    for (int r = 0; r < 16; ++r){
                        int d = 32 * t + (r & 3) + 8 * (r >> 2) + 4 * hi;
                        x_lds[d * BT + 32 + ln] = acc1[r];
                    }
                } else if (hi == 0){
                    *(float4*)(out + (size_t)(b0 + 32 + ln) * 4) =
                        make_float4(acc1[12], acc1[13], acc1[14], acc1[15]);
                }
            }
        }
        // next iteration's barrier (A) orders x writes vs bpack reads
    }
}

extern "C" void kernel_launch(void* const* d_in, const int* in_sizes, int n_in,
                              void* d_out, int out_size, void* d_ws, size_t ws_size,
                              hipStream_t stream)
{
    const float* X  = (const float*)d_in[0];
    const float* W  = (const float*)d_in[1];
    const float* ti = (const float*)d_in[2];
    const float* li = (const float*)d_in[3];
    float* out      = (float*)d_out;
    short8* A       = (short8*)d_ws;           // 4*585*64*16 B = 2.40 MB

    const int ntotal = 4 * 130 * 8 * 64;
    prep_kernel<<<(ntotal + 255) / 256, 256, 0, stream>>>(W, A);
    taylor_kernel<<<BATCH / BT, 512, 0, stream>>>(X, W, ti, li, A, out);
}

// Round 3
// 316.693 us; speedup vs baseline: 1.5615x; 1.0162x over previous
//
#include <hip/hip_runtime.h>
#include <hip/hip_bf16.h>

// TaylorMap, symmetric-packed quadratic, uniform-9 pair stream (bf16).
// R15 = R12 core EXACTLY (proven 254 us, zero-spill 128-VGPR shape;
// R13's reg-pipeline spilled, R14's skew bundle was neutral-negative)
// + two surgical diffs:
//   (1) lgkmcnt-only barriers: __syncthreads() lowers to
//       s_waitcnt vmcnt(0) lgkmcnt(0); s_barrier -- a full A-prefetch
//       drain 3x/step (T4 anti-pattern). Every cross-wave dep at these
//       barriers is LDS (x_lds/bpack/sc_lds ds_writes), so lgkmcnt(0)
//       alone is sufficient; compiler still emits counted vmcnt before
//       each abuf use. The A-stream never fully drains.
//   (2) g0 last-pair peel: pair 31's 9 trailing reloads fetched discarded
//       pair-32 data (1.5% of fill traffic). g1 keeps its tail reloads
//       (they feed the linear chain).
// Discriminates: drain-stall (H2 -> 238-246 us) vs hard ~33 B/cyc/CU
// vector-load path ceiling (H1 -> neutral, 254 us is the roofline:
// fill 2.34 MB/CU/step = 74k cyc ~= 76k measured wall).

#define DSTATE 128
#define BATCH  16384
#define NSTEPS 7
#define BT     64
#define NSL    585          // slices per d-tile: 64*9 pair + 8 linear + 1 pad

typedef __attribute__((ext_vector_type(8)))  short  short8;   // 8 bf16 = 4 VGPRs
typedef __attribute__((ext_vector_type(16))) float  f32x16;   // MFMA 32x32 C/D

__device__ __forceinline__ unsigned short f2bf(float f){
    unsigned int u = __float_as_uint(f);
    u += 0x7fff + ((u >> 16) & 1);          // RNE
    return (unsigned short)(u >> 16);
}

// lgkmcnt-only workgroup barrier: drains LDS ops, NOT the vmem queue.
__device__ __forceinline__ void barrier_lgkm(){
    asm volatile("s_waitcnt lgkmcnt(0)" ::: "memory");
    __builtin_amdgcn_s_barrier();
}

// Pack symmetric-folded W into bf16 MFMA-A fragments, uniform-9 pair stream.
// Pair p at positions 9p..9p+8: first 8-(p>>4) slices are row p (j-blocks
// p>>4..7), remaining 1+(p>>4) are row 127-p (j-blocks 7-(p>>4)..7).
// Fragment layout: A[m][k], m=lane&31 -> d=32t+m, k=(lane>>5)*8+e -> j=16*s+k.
__global__ void prep_kernel(const float* __restrict__ W, short8* __restrict__ A){
    int gid = blockIdx.x * 256 + threadIdx.x;
    const int ntotal = 4 * 130 * 8 * 64;
    if (gid >= ntotal) return;
    int lane = gid & 63; int r = gid >> 6;
    int s = r & 7;  r >>= 3;
    int row = r % 130;
    int t   = r / 130;
    int d  = t * 32 + (lane & 31);
    int kb = (lane >> 5) * 8;
    int dst;
    bool zero = false;
    if (row < 64){
        int sl = row >> 4;
        if (s < sl) return;
        dst = t * NSL + 9 * row + (s - sl);
    } else if (row < 128){
        int p  = 127 - row;
        int sl = row >> 4;
        if (s < sl) return;
        int ca = 8 - (p >> 4);
        dst = t * NSL + 9 * p + ca + (s - sl);
    } else if (row == 128){
        dst = t * NSL + 576 + s;               // linear (W1) row
    } else {
        if (s) return;                         // zero pad slice
        dst = t * NSL + 584;
        zero = true;
    }
    union { short8 v; unsigned short u[8]; } fr;
#pragma unroll
    for (int e = 0; e < 8; ++e){
        int j = s * 16 + kb + e;
        float v;
        if (zero) v = 0.0f;
        else if (row < 128){
            if      (j < row)  v = 0.0f;
            else if (j == row) v = W[(129 + 128 * row + j) * 128 + d];
            else               v = W[(129 + 128 * row + j) * 128 + d]
                                 + W[(129 + 128 * j + row) * 128 + d];
        } else {
            v = W[(1 + j) * 128 + d];
        }
        fr.u[e] = f2bf(v);
    }
    A[(size_t)dst * 64 + lane] = fr.v;
}

__global__ __launch_bounds__(512)
void taylor_kernel(const float* __restrict__ X, const float* __restrict__ W,
                   const float* __restrict__ tini, const float* __restrict__ lini,
                   const short8* __restrict__ A, float* __restrict__ out)
{
    __shared__ float  x_lds[DSTATE * BT];      // fp32 master state [d][b], 32 KB
    __shared__ float  w0_lds[DSTATE];
    __shared__ short8 bpack[2 * 8 * 64];       // B frags, 2 groups x 8 slices, 16 KB
    __shared__ float  sc_lds[2][4 * 64 * 17];  // K-merge scratch, 34.8 KB

    const int tid  = threadIdx.x;
    const int lane = tid & 63;
    const int w    = tid >> 6;
    const int t    = w & 3;                    // d-tile
    const int g    = w >> 2;                   // K-half (pairs 0..31 / 32..63+lin)
    const int ln   = lane & 31;
    const int hi   = lane >> 5;
    const int b0   = blockIdx.x * BT;

    // ---- init x0 = [X | t_init | l_init] ----
#pragma unroll
    for (int it = 0; it < 16; ++it){
        int entry = tid + it * 512;            // entry = b*128 + d
        int b = entry >> 7, d = entry & 127;
        float v;
        if      (d < 120) v = X[(b0 + b) * 120 + d];
        else if (d < 124) v = tini[d - 120];
        else              v = lini[d - 124];
        x_lds[d * BT + b] = v;
    }
    if (tid < DSTATE) w0_lds[tid] = W[tid];

    // wave's half-stream base: g0 -> slice 0, g1 -> slice 288 (pair 32)
    const short8* const Aw = A + ((size_t)t * NSL + (size_t)g * 288) * 64 + lane;
    const f32x16 zero16 = {};

#pragma unroll 1
    for (int step = 0; step < NSTEPS; ++step){
        barrier_lgkm();                        // (A) x_lds stable

        // last-step pruning: only d-tile 3 feeds out dims 120..123
        const bool active = (step < NSTEPS - 1) || (t == 3);

        const short8* ap = Aw;
        short8 abuf[9];
        if (active){
#pragma unroll
            for (int s = 0; s < 9; ++s) abuf[s] = ap[s * 64];
            ap += 9 * 64;
        }

        // ---- build bpack (1024 frags, 2 per thread) while loads fly ----
#pragma unroll
        for (int f0 = 0; f0 < 2; ++f0){
            int f  = tid + f0 * 512;
            int gg = f >> 9, s = (f >> 6) & 7, l = f & 63;
            int c  = gg * 32 + (l & 31);
            int jb = 16 * s + 8 * (l >> 5);
            union { short8 v; unsigned short u[8]; } fr;
#pragma unroll
            for (int e = 0; e < 8; ++e)
                fr.u[e] = f2bf(x_lds[(jb + e) * BT + c]);
            bpack[f] = fr.v;
        }

        // ---- acc: g0 carries x_old + W0 for both groups; g1 pure partial ----
        f32x16 acc0, acc1;
        if (active){
            if (g == 0){
#pragma unroll
                for (int r = 0; r < 16; ++r){
                    int d = 32 * t + (r & 3) + 8 * (r >> 2) + 4 * hi;
                    acc0[r] = x_lds[d * BT + ln]      + w0_lds[d];
                    acc1[r] = x_lds[d * BT + 32 + ln] + w0_lds[d];
                }
            } else {
#pragma unroll
                for (int r = 0; r < 16; ++r){ acc0[r] = 0.f; acc1[r] = 0.f; }
            }
        }

        barrier_lgkm();                        // (B) bpack visible

        if (active){
            short8 bfrag0[8], bfrag1[8];       // B reg-cache for current BK block

            // R9 core: pair p=16*BK+q, rows (p,127-p). Y: slices BK..7
            // (abuf[0..7-BK]); Z: slices 7-BK..7 (abuf[8-BK..8], bfrag
            // 7-2BK+s). Immediate chain-end fmacs (proven zero-spill shape).
            // abuf[s] reloaded for the NEXT pair right after its consumers.
            // NQ = pairs executed with trailing reloads (16, or 15 + peel).
#define PAIRS(BK, NQ)                                                           \
            {                                                                   \
                _Pragma("unroll")                                               \
                for (int s = 0; s < 8 - (BK); ++s){                             \
                    bfrag0[s] = bpack[((BK) + s) * 64 + lane];                  \
                    bfrag1[s] = bpack[512 + ((BK) + s) * 64 + lane];            \
                }                                                               \
                _Pragma("unroll 2")                                             \
                for (int q = 0; q < (NQ); ++q){                                 \
                    const int p = 16 * (BK) + q;                                \
                    float s0a = x_lds[p * BT + ln];                             \
                    float s0b = x_lds[p * BT + 32 + ln];                        \
                    float s1a = x_lds[(127 - p) * BT + ln];                     \
                    float s1b = x_lds[(127 - p) * BT + 32 + ln];                \
                    f32x16 Y0, Y1;                                              \
                    _Pragma("unroll")                                           \
                    for (int s = 0; s < 8 - (BK); ++s){                         \
                        Y0 = __builtin_amdgcn_mfma_f32_32x32x16_bf16(abuf[s], bfrag0[s], s ? Y0 : zero16, 0, 0, 0); \
                        Y1 = __builtin_amdgcn_mfma_f32_32x32x16_bf16(abuf[s], bfrag1[s], s ? Y1 : zero16, 0, 0, 0); \
                        abuf[s] = ap[s * 64];                                   \
                    }                                                           \
                    acc0 += s0a * Y0;                                           \
                    acc1 += s0b * Y1;                                           \
                    f32x16 Z0, Z1;                                              \
                    _Pragma("unroll")                                           \
                    for (int s = 0; s < 1 + (BK); ++s){                         \
                        Z0 = __builtin_amdgcn_mfma_f32_32x32x16_bf16(abuf[8 - (BK) + s], bfrag0[7 - 2 * (BK) + s], s ? Z0 : zero16, 0, 0, 0); \
                        Z1 = __builtin_amdgcn_mfma_f32_32x32x16_bf16(abuf[8 - (BK) + s], bfrag1[7 - 2 * (BK) + s], s ? Z1 : zero16, 0, 0, 0); \
                        abuf[8 - (BK) + s] = ap[(8 - (BK) + s) * 64];           \
                    }                                                           \
                    acc0 += s1a * Z0;                                           \
                    acc1 += s1b * Z1;                                           \
                    ap += 9 * 64;                                               \
                }                                                               \
            }

            // Final pair of a wave's stream: no trailing reloads (they would
            // fetch discarded data). Same Y/Z chains, fixed p.
#define QTAIL(BK, PP)                                                           \
            {                                                                   \
                const int p = (PP);                                             \
                float s0a = x_lds[p * BT + ln];                                 \
                float s0b = x_lds[p * BT + 32 + ln];                            \
                float s1a = x_lds[(127 - p) * BT + ln];                         \
                float s1b = x_lds[(127 - p) * BT + 32 + ln];                    \
                f32x16 Y0, Y1;                                                  \
                _Pragma("unroll")                                               \
                for (int s = 0; s < 8 - (BK); ++s){                             \
                    Y0 = __builtin_amdgcn_mfma_f32_32x32x16_bf16(abuf[s], bfrag0[s], s ? Y0 : zero16, 0, 0, 0); \
                    Y1 = __builtin_amdgcn_mfma_f32_32x32x16_bf16(abuf[s], bfrag1[s], s ? Y1 : zero16, 0, 0, 0); \
                }                                                               \
                acc0 += s0a * Y0;                                               \
                acc1 += s0b * Y1;                                               \
                f32x16 Z0, Z1;                                                  \
                _Pragma("unroll")                                               \
                for (int s = 0; s < 1 + (BK); ++s){                             \
                    Z0 = __builtin_amdgcn_mfma_f32_32x32x16_bf16(abuf[8 - (BK) + s], bfrag0[7 - 2 * (BK) + s], s ? Z0 : zero16, 0, 0, 0); \
                    Z1 = __builtin_amdgcn_mfma_f32_32x32x16_bf16(abuf[8 - (BK) + s], bfrag1[7 - 2 * (BK) + s], s ? Z1 : zero16, 0, 0, 0); \
                }                                                               \
                acc0 += s1a * Z0;                                               \
                acc1 += s1b * Z1;                                               \
            }

            if (g == 0){
                PAIRS(0, 16)
                PAIRS(1, 15)
                QTAIL(1, 31)                   // peeled: no garbage reloads
                // publish K-half partials
            } else {
                PAIRS(2, 16)
                PAIRS(3, 16)
                // pair 63's trailing reloads pulled slices 576..584 (linear
                // row + pad) into abuf -- consumed below, nothing wasted.
                // linear (W1) row: scale==1 -> accumulate DIRECTLY into acc
                // via the MFMA C-operand
#pragma unroll
                for (int s = 0; s < 8; ++s){
                    bfrag0[s] = bpack[s * 64 + lane];
                    bfrag1[s] = bpack[512 + s * 64 + lane];
                }
#pragma unroll
                for (int s = 0; s < 8; ++s){
                    acc0 = __builtin_amdgcn_mfma_f32_32x32x16_bf16(abuf[s], bfrag0[s], acc0, 0, 0, 0);
                    acc1 = __builtin_amdgcn_mfma_f32_32x32x16_bf16(abuf[s], bfrag1[s], acc1, 0, 0, 0);
                }
            }
            if (g == 1){
                // publish K-half partials
#pragma unroll
                for (int r = 0; r < 16; ++r){
                    sc_lds[0][(t * 64 + lane) * 17 + r] = acc0[r];
                    sc_lds[1][(t * 64 + lane) * 17 + r] = acc1[r];
                }
            }
#undef PAIRS
#undef QTAIL
        }

        barrier_lgkm();                        // (C) reads done + scratch visible
        if (active && g == 0){
#pragma unroll
            for (int r = 0; r < 16; ++r){
                acc0[r] += sc_lds[0][(t * 64 + lane) * 17 + r];
                acc1[r] += sc_lds[1][(t * 64 + lane) * 17 + r];
            }
            if (step < NSTEPS - 1){
#pragma unroll
                for (int r = 0; r < 16; ++r){
                    int d = 32 * t + (r & 3) + 8 * (r >> 2) + 4 * hi;
                    x_lds[d * BT + ln]      = acc0[r];
                    x_lds[d * BT + 32 + ln] = acc1[r];
                }
            } else if (hi == 0){
                // out dims 120..123 -> tile 3, regs 12..15 @ hi==0
                *(float4*)(out + (size_t)(b0 + ln) * 4) =
                    make_float4(acc0[12], acc0[13], acc0[14], acc0[15]);
                *(float4*)(out + (size_t)(b0 + 32 + ln) * 4) =
                    make_float4(acc1[12], acc1[13], acc1[14], acc1[15]);
            }
        }
        // next iteration's barrier (A) orders g0's x write vs g1's next reads
    }
}

extern "C" void kernel_launch(void* const* d_in, const int* in_sizes, int n_in,
                              void* d_out, int out_size, void* d_ws, size_t ws_size,
                              hipStream_t stream)
{
    const float* X  = (const float*)d_in[0];
    const float* W  = (const float*)d_in[1];
    const float* ti = (const float*)d_in[2];
    const float* li = (const float*)d_in[3];
    float* out      = (float*)d_out;
    short8* A       = (short8*)d_ws;           // 4*585*64*16 B = 2.40 MB

    const int ntotal = 4 * 130 * 8 * 64;
    prep_kernel<<<(ntotal + 255) / 256, 256, 0, stream>>>(W, A);
    taylor_kernel<<<BATCH / BT, 512, 0, stream>>>(X, W, ti, li, A, out);
}